// Round 5
// baseline (158.484 us; speedup 1.0000x reference)
//
#include <hip/hip_runtime.h>
#include <hip/hip_fp16.h>

#define NLEV 8
#define BASE 512

typedef _Float16 h8 __attribute__((ext_vector_type(8)));
typedef float f4v __attribute__((ext_vector_type(4)));

// half-offset of fp16 mip level k (k in [1,7]) within ws; texel = 16 halves.
__host__ __device__ __forceinline__ long moff(int k) {
    return 4194304L - (4194304L >> (2 * k - 2));
}
#define MIPS_HALVES 4194048L           // moff(8)
#define L0_OFF      MIPS_HALVES        // fp16 copy of level 0 lives after the mips
#define L0_HALVES   12582912L          // 3*512*512*16
#define WS_NEED_FULL ((L0_OFF + L0_HALVES) * 2)

// Convert f32 level-0 texture -> fp16 copy. One thread per 8 floats.
__global__ __launch_bounds__(256) void cvt0(const float* __restrict__ src,
                                            _Float16* __restrict__ dst) {
    long idx = (long)blockIdx.x * blockDim.x + threadIdx.x;
    if (idx >= L0_HALVES / 8) return;
    const f4v* s = (const f4v*)src;
    f4v a = s[idx * 2], b = s[idx * 2 + 1];
    h8 o;
    o[0] = (_Float16)a[0]; o[1] = (_Float16)a[1]; o[2] = (_Float16)a[2]; o[3] = (_Float16)a[3];
    o[4] = (_Float16)b[0]; o[5] = (_Float16)b[1]; o[6] = (_Float16)b[2]; o[7] = (_Float16)b[3];
    ((h8*)dst)[idx] = o;
}

// Build mip1 (fp16) directly from the f32 texture.
__global__ __launch_bounds__(256) void ds16_first(const float* __restrict__ src,
                                                  _Float16* __restrict__ dst, int r2) {
    int idx = blockIdx.x * blockDim.x + threadIdx.x;
    int total = 3 * r2 * r2 * 2;
    if (idx >= total) return;
    int g = idx & 1;
    int rest = idx >> 1;
    int u = rest % r2; rest /= r2;
    int v = rest % r2;
    int p = rest / r2;
    int rs = r2 * 2;
    const f4v* s4 = (const f4v*)src;
    long t00 = ((long)p * rs + 2 * v) * rs + 2 * u;   // src texel index
    long t01 = t00 + 1, t10 = t00 + rs, t11 = t10 + 1;
    f4v a0 = s4[t00 * 4 + g * 2], a1 = s4[t00 * 4 + g * 2 + 1];
    f4v b0 = s4[t01 * 4 + g * 2], b1 = s4[t01 * 4 + g * 2 + 1];
    f4v c0 = s4[t10 * 4 + g * 2], c1 = s4[t10 * 4 + g * 2 + 1];
    f4v d0 = s4[t11 * 4 + g * 2], d1 = s4[t11 * 4 + g * 2 + 1];
    h8 o;
#pragma unroll
    for (int j = 0; j < 4; ++j) {
        o[j]     = (_Float16)((a0[j] + b0[j] + c0[j] + d0[j]) * 0.25f);
        o[4 + j] = (_Float16)((a1[j] + b1[j] + c1[j] + d1[j]) * 0.25f);
    }
    ((h8*)dst)[idx] = o;
}

// Downsample fp16 mip -> fp16 mip (accumulate in f32).
__global__ __launch_bounds__(256) void ds16(const _Float16* __restrict__ src,
                                            _Float16* __restrict__ dst, int r2) {
    int idx = blockIdx.x * blockDim.x + threadIdx.x;
    int total = 3 * r2 * r2 * 2;
    if (idx >= total) return;
    int g = idx & 1;
    int rest = idx >> 1;
    int u = rest % r2; rest /= r2;
    int v = rest % r2;
    int p = rest / r2;
    int rs = r2 * 2;
    const h8* s8 = (const h8*)src;
    long t00 = ((long)p * rs + 2 * v) * rs + 2 * u;
    long t01 = t00 + 1, t10 = t00 + rs, t11 = t10 + 1;
    h8 A = s8[t00 * 2 + g], B = s8[t01 * 2 + g], C = s8[t10 * 2 + g], D = s8[t11 * 2 + g];
    h8 o;
#pragma unroll
    for (int j = 0; j < 8; ++j)
        o[j] = (_Float16)(((float)A[j] + (float)B[j] + (float)C[j] + (float)D[j]) * 0.25f);
    ((h8*)dst)[idx] = o;
}

// Sampling: 4 lanes per point. lane = i*4 + usel*2 + fg.
// fg owns 8 features (16 B fp16); usel owns the u-column.
// __launch_bounds__(256, 4): allow up to 128 VGPRs so ALL 12 texel gathers
// can be in flight simultaneously (latency hiding via ILP).
template <bool L0F16>
__global__ __launch_bounds__(256, 4) void tm_sample4(const float* __restrict__ x,
                                                     const float* __restrict__ level,
                                                     const float* __restrict__ tex0,
                                                     const _Float16* __restrict__ wsh,
                                                     float* __restrict__ out, int n) {
    int t = blockIdx.x * blockDim.x + threadIdx.x;
    int i = t >> 2;
    if (i >= n) return;
    int fg = t & 1;
    int usel = (t >> 1) & 1;

    float px = x[3 * i + 0];
    float py = x[3 * i + 1];
    float pz = x[3 * i + 2];
    float lev = fminf(fmaxf(level[i], 0.0f), (float)(NLEV - 1));
    float l0f = floorf(lev);
    float frac = lev - l0f;
    int l0 = (int)l0f;
    int k1 = min(l0 + 1, NLEV - 1);    // always >= 1

    float uu[3] = {py, px, px};
    float vv[3] = {pz, pz, py};
    int rr[2] = {BASE >> l0, BASE >> k1};

    const _Float16* texs[2];
    texs[0] = (l0 == 0) ? (wsh + L0_OFF) : (wsh + moff(l0));
    texs[1] = wsh + moff(k1);

    h8 tvh[2][3][2];      // [lev][plane][vrow] this lane's 8 features
    float wu[2][3];       // lane's u weight
    float fvv[2][3];      // v fraction

#pragma unroll
    for (int s = 0; s < 2; ++s) {
        int r = rr[s];
        float rf = (float)r;
        const h8* t8 = (const h8*)texs[s];
        bool f32path = (!L0F16) && (s == 0) && (l0 == 0);
#pragma unroll
        for (int p = 0; p < 3; ++p) {
            float cu = uu[p] * rf - 0.5f;
            float cv = vv[p] * rf - 0.5f;
            float fu0 = floorf(cu), fv0 = floorf(cv);
            float fu = cu - fu0, fv = cv - fv0;
            int iu0 = (int)fu0, iv0 = (int)fv0;
            int u0 = min(max(iu0, 0), r - 1);
            int u1 = min(max(iu0 + 1, 0), r - 1);
            int v0 = min(max(iv0, 0), r - 1);
            int v1 = min(max(iv0 + 1, 0), r - 1);
            int u = usel ? u1 : u0;
            wu[s][p] = usel ? fu : (1.0f - fu);
            fvv[s][p] = fv;
            long pb = (long)p * r * r;
            long ti0 = pb + (long)v0 * r + u;
            long ti1 = pb + (long)v1 * r + u;
            if (f32path) {
                const f4v* t4 = (const f4v*)tex0;
                f4v a = t4[ti0 * 4 + fg * 2], b = t4[ti0 * 4 + fg * 2 + 1];
                f4v c = t4[ti1 * 4 + fg * 2], d = t4[ti1 * 4 + fg * 2 + 1];
                h8 A, B;
#pragma unroll
                for (int j = 0; j < 4; ++j) {
                    A[j] = (_Float16)a[j]; A[4 + j] = (_Float16)b[j];
                    B[j] = (_Float16)c[j]; B[4 + j] = (_Float16)d[j];
                }
                tvh[s][p][0] = A;
                tvh[s][p][1] = B;
            } else {
                tvh[s][p][0] = t8[ti0 * 2 + fg];
                tvh[s][p][1] = t8[ti1 * 2 + fg];
            }
        }
    }

    float lw[2] = {1.0f - frac, frac};
    float acc[3][8];
#pragma unroll
    for (int p = 0; p < 3; ++p)
#pragma unroll
        for (int j = 0; j < 8; ++j) acc[p][j] = 0.f;

#pragma unroll
    for (int s = 0; s < 2; ++s)
#pragma unroll
        for (int p = 0; p < 3; ++p) {
            float w0 = (1.0f - fvv[s][p]) * wu[s][p] * lw[s];
            float w1 = fvv[s][p] * wu[s][p] * lw[s];
#pragma unroll
            for (int j = 0; j < 8; ++j)
                acc[p][j] += (float)tvh[s][p][0][j] * w0 + (float)tvh[s][p][1][j] * w1;
        }

    // merge u0/u1 partials across the usel pair (lane ^ 2)
#pragma unroll
    for (int p = 0; p < 3; ++p)
#pragma unroll
        for (int j = 0; j < 8; ++j)
            acc[p][j] += __shfl_xor(acc[p][j], 2, 64);

    // out[i*48 + p*16 + fg*8 + j]; as f4v: index i*12 + p*4 + fg*2 (+1)
    // Normal (cached) stores: let L2 write-combine the exec-masked partial lines.
    f4v* o4 = (f4v*)out;
    long ob = (long)i * 12 + fg * 2;
    if (usel == 0) {
        f4v r0 = {acc[0][0], acc[0][1], acc[0][2], acc[0][3]};
        f4v r1 = {acc[0][4], acc[0][5], acc[0][6], acc[0][7]};
        f4v r4 = {acc[2][0], acc[2][1], acc[2][2], acc[2][3]};
        f4v r5 = {acc[2][4], acc[2][5], acc[2][6], acc[2][7]};
        o4[ob + 0] = r0;
        o4[ob + 1] = r1;
        o4[ob + 8] = r4;
        o4[ob + 9] = r5;
    } else {
        f4v r2 = {acc[1][0], acc[1][1], acc[1][2], acc[1][3]};
        f4v r3 = {acc[1][4], acc[1][5], acc[1][6], acc[1][7]};
        o4[ob + 4] = r2;
        o4[ob + 5] = r3;
    }
}

extern "C" void kernel_launch(void* const* d_in, const int* in_sizes, int n_in,
                              void* d_out, int out_size, void* d_ws, size_t ws_size,
                              hipStream_t stream) {
    const float* x     = (const float*)d_in[0];
    const float* level = (const float*)d_in[1];
    const float* tex   = (const float*)d_in[2];
    float* out = (float*)d_out;
    _Float16* wsh = (_Float16*)d_ws;
    int n = in_sizes[0] / 3;

    bool full = ws_size >= (size_t)WS_NEED_FULL;

    // mip 1 from f32 texture
    {
        int r2 = BASE >> 1;
        int total = 3 * r2 * r2 * 2;
        ds16_first<<<(total + 255) / 256, 256, 0, stream>>>(tex, wsh + moff(1), r2);
    }
    // mips 2..7 from previous fp16 mip
    for (int k = 2; k < NLEV; ++k) {
        int r2 = BASE >> k;
        int total = 3 * r2 * r2 * 2;
        ds16<<<(total + 255) / 256, 256, 0, stream>>>(wsh + moff(k - 1), wsh + moff(k), r2);
    }
    // fp16 copy of level 0 (only if workspace fits)
    if (full) {
        long tot = L0_HALVES / 8;
        cvt0<<<(int)((tot + 255) / 256), 256, 0, stream>>>(tex, wsh + L0_OFF);
    }

    long tt = (long)n * 4;
    int blocks = (int)((tt + 255) / 256);
    if (full)
        tm_sample4<true><<<blocks, 256, 0, stream>>>(x, level, tex, wsh, out, n);
    else
        tm_sample4<false><<<blocks, 256, 0, stream>>>(x, level, tex, wsh, out, n);
}

// Round 6
// 152.015 us; speedup vs baseline: 1.0426x; 1.0426x over previous
//
#include <hip/hip_runtime.h>
#include <hip/hip_fp16.h>

#define NLEV 8
#define BASE 512

typedef _Float16 h8 __attribute__((ext_vector_type(8)));
typedef float f4v __attribute__((ext_vector_type(4)));
typedef int  i4v __attribute__((ext_vector_type(4)));

// half-offset of fp16 mip level k (k in [1,7]) within ws; texel = 16 halves.
__host__ __device__ __forceinline__ long moff(int k) {
    return 4194304L - (4194304L >> (2 * k - 2));
}
#define MIPS_HALVES 4194048L           // moff(8)
#define L0_OFF      MIPS_HALVES        // fp16 copy of level 0 lives after the mips
#define L0_HALVES   12582912L          // 3*512*512*16
#define WS_NEED_FULL ((L0_OFF + L0_HALVES) * 2)

// Fused: f32 L0 -> fp16 L0 copy AND fp16 mip1, single pass over the 48 MB input.
// One thread per 8-feature half of one mip1 texel (reads 4 src texel-halves).
__global__ __launch_bounds__(256) void cvt_ds1(const float* __restrict__ src,
                                               _Float16* __restrict__ l0,
                                               _Float16* __restrict__ m1) {
    int idx = blockIdx.x * blockDim.x + threadIdx.x;
    const int r2 = BASE / 2;
    int total = 3 * r2 * r2 * 2;
    if (idx >= total) return;
    int g = idx & 1;
    int rest = idx >> 1;
    int u = rest % r2; rest /= r2;
    int v = rest % r2;
    int p = rest / r2;
    const int rs = BASE;
    const f4v* s4 = (const f4v*)src;
    long t00 = ((long)p * rs + 2 * v) * rs + 2 * u;   // src texel index
    long t01 = t00 + 1, t10 = t00 + rs, t11 = t10 + 1;
    f4v a0 = s4[t00 * 4 + g * 2], a1 = s4[t00 * 4 + g * 2 + 1];
    f4v b0 = s4[t01 * 4 + g * 2], b1 = s4[t01 * 4 + g * 2 + 1];
    f4v c0 = s4[t10 * 4 + g * 2], c1 = s4[t10 * 4 + g * 2 + 1];
    f4v d0 = s4[t11 * 4 + g * 2], d1 = s4[t11 * 4 + g * 2 + 1];
    h8 H00, H01, H10, H11, o;
#pragma unroll
    for (int j = 0; j < 4; ++j) {
        H00[j] = (_Float16)a0[j]; H00[4 + j] = (_Float16)a1[j];
        H01[j] = (_Float16)b0[j]; H01[4 + j] = (_Float16)b1[j];
        H10[j] = (_Float16)c0[j]; H10[4 + j] = (_Float16)c1[j];
        H11[j] = (_Float16)d0[j]; H11[4 + j] = (_Float16)d1[j];
        o[j]     = (_Float16)((a0[j] + b0[j] + c0[j] + d0[j]) * 0.25f);
        o[4 + j] = (_Float16)((a1[j] + b1[j] + c1[j] + d1[j]) * 0.25f);
    }
    h8* l8 = (h8*)l0;
    l8[t00 * 2 + g] = H00;
    l8[t01 * 2 + g] = H01;
    l8[t10 * 2 + g] = H10;
    l8[t11 * 2 + g] = H11;
    ((h8*)m1)[idx] = o;
}

// Fallback first-mip (no fp16 L0 copy) when workspace is too small.
__global__ __launch_bounds__(256) void ds16_first(const float* __restrict__ src,
                                                  _Float16* __restrict__ dst, int r2) {
    int idx = blockIdx.x * blockDim.x + threadIdx.x;
    int total = 3 * r2 * r2 * 2;
    if (idx >= total) return;
    int g = idx & 1;
    int rest = idx >> 1;
    int u = rest % r2; rest /= r2;
    int v = rest % r2;
    int p = rest / r2;
    int rs = r2 * 2;
    const f4v* s4 = (const f4v*)src;
    long t00 = ((long)p * rs + 2 * v) * rs + 2 * u;
    long t01 = t00 + 1, t10 = t00 + rs, t11 = t10 + 1;
    f4v a0 = s4[t00 * 4 + g * 2], a1 = s4[t00 * 4 + g * 2 + 1];
    f4v b0 = s4[t01 * 4 + g * 2], b1 = s4[t01 * 4 + g * 2 + 1];
    f4v c0 = s4[t10 * 4 + g * 2], c1 = s4[t10 * 4 + g * 2 + 1];
    f4v d0 = s4[t11 * 4 + g * 2], d1 = s4[t11 * 4 + g * 2 + 1];
    h8 o;
#pragma unroll
    for (int j = 0; j < 4; ++j) {
        o[j]     = (_Float16)((a0[j] + b0[j] + c0[j] + d0[j]) * 0.25f);
        o[4 + j] = (_Float16)((a1[j] + b1[j] + c1[j] + d1[j]) * 0.25f);
    }
    ((h8*)dst)[idx] = o;
}

// Downsample fp16 mip -> fp16 mip (accumulate in f32).
__global__ __launch_bounds__(256) void ds16(const _Float16* __restrict__ src,
                                            _Float16* __restrict__ dst, int r2) {
    int idx = blockIdx.x * blockDim.x + threadIdx.x;
    int total = 3 * r2 * r2 * 2;
    if (idx >= total) return;
    int g = idx & 1;
    int rest = idx >> 1;
    int u = rest % r2; rest /= r2;
    int v = rest % r2;
    int p = rest / r2;
    int rs = r2 * 2;
    const h8* s8 = (const h8*)src;
    long t00 = ((long)p * rs + 2 * v) * rs + 2 * u;
    long t01 = t00 + 1, t10 = t00 + rs, t11 = t10 + 1;
    h8 A = s8[t00 * 2 + g], B = s8[t01 * 2 + g], C = s8[t10 * 2 + g], D = s8[t11 * 2 + g];
    h8 o;
#pragma unroll
    for (int j = 0; j < 8; ++j)
        o[j] = (_Float16)(((float)A[j] + (float)B[j] + (float)C[j] + (float)D[j]) * 0.25f);
    ((h8*)dst)[idx] = o;
}

// Sampling: 4 lanes per point. lane = i*4 + usel*2 + fg.
// All 12 texel gathers are force-issued via inline asm, then one vmcnt(0)
// that carries the 12 destinations as dataflow operands (no hoisting).
__global__ __launch_bounds__(256, 4) void tm_sample_asm(const float* __restrict__ x,
                                                        const float* __restrict__ level,
                                                        const _Float16* __restrict__ wsh,
                                                        float* __restrict__ out, int n) {
    int t = blockIdx.x * blockDim.x + threadIdx.x;
    int i = t >> 2;
    if (i >= n) return;
    int fg = t & 1;
    int usel = (t >> 1) & 1;

    float px = x[3 * i + 0];
    float py = x[3 * i + 1];
    float pz = x[3 * i + 2];
    float lev = fminf(fmaxf(level[i], 0.0f), (float)(NLEV - 1));
    float l0f = floorf(lev);
    float frac = lev - l0f;
    int l0 = (int)l0f;
    int k1 = min(l0 + 1, NLEV - 1);

    float uu[3] = {py, px, px};
    float vv[3] = {pz, pz, py};
    int rr[2] = {BASE >> l0, BASE >> k1};
    const _Float16* texs[2];
    texs[0] = (l0 == 0) ? (wsh + L0_OFF) : (wsh + moff(l0));
    texs[1] = wsh + moff(k1);

    const _Float16* ap[12];
    float wu[2][3];
    float fvv[2][3];

#pragma unroll
    for (int s = 0; s < 2; ++s) {
        int r = rr[s];
        float rf = (float)r;
#pragma unroll
        for (int p = 0; p < 3; ++p) {
            float cu = uu[p] * rf - 0.5f;
            float cv = vv[p] * rf - 0.5f;
            float fu0 = floorf(cu), fv0 = floorf(cv);
            float fu = cu - fu0, fv = cv - fv0;
            int iu0 = (int)fu0, iv0 = (int)fv0;
            int u0 = min(max(iu0, 0), r - 1);
            int u1 = min(max(iu0 + 1, 0), r - 1);
            int v0 = min(max(iv0, 0), r - 1);
            int v1 = min(max(iv0 + 1, 0), r - 1);
            int u_ = usel ? u1 : u0;
            wu[s][p] = usel ? fu : (1.0f - fu);
            fvv[s][p] = fv;
            long pb = (long)p * r * r;
            long ti0 = pb + (long)v0 * r + u_;
            long ti1 = pb + (long)v1 * r + u_;
            ap[s * 6 + p * 2 + 0] = texs[s] + ti0 * 16 + fg * 8;   // halves
            ap[s * 6 + p * 2 + 1] = texs[s] + ti1 * 16 + fg * 8;
        }
    }

    i4v d[12];
#pragma unroll
    for (int k = 0; k < 12; ++k)
        asm volatile("global_load_dwordx4 %0, %1, off"
                     : "=v"(d[k]) : "v"(ap[k]) : "memory");
    asm volatile("s_waitcnt vmcnt(0)"
                 : "+v"(d[0]), "+v"(d[1]), "+v"(d[2]), "+v"(d[3]),
                   "+v"(d[4]), "+v"(d[5]), "+v"(d[6]), "+v"(d[7]),
                   "+v"(d[8]), "+v"(d[9]), "+v"(d[10]), "+v"(d[11])
                 :: "memory");

    float lw[2] = {1.0f - frac, frac};
    float acc[3][8];
#pragma unroll
    for (int p = 0; p < 3; ++p)
#pragma unroll
        for (int j = 0; j < 8; ++j) acc[p][j] = 0.f;

#pragma unroll
    for (int s = 0; s < 2; ++s)
#pragma unroll
        for (int p = 0; p < 3; ++p) {
            h8 T0 = __builtin_bit_cast(h8, d[s * 6 + p * 2 + 0]);
            h8 T1 = __builtin_bit_cast(h8, d[s * 6 + p * 2 + 1]);
            float w0 = (1.0f - fvv[s][p]) * wu[s][p] * lw[s];
            float w1 = fvv[s][p] * wu[s][p] * lw[s];
#pragma unroll
            for (int j = 0; j < 8; ++j)
                acc[p][j] += (float)T0[j] * w0 + (float)T1[j] * w1;
        }

    // merge u0/u1 partials across the usel pair (lane ^ 2)
#pragma unroll
    for (int p = 0; p < 3; ++p)
#pragma unroll
        for (int j = 0; j < 8; ++j)
            acc[p][j] += __shfl_xor(acc[p][j], 2, 64);

    // out[i*48 + p*16 + fg*8 + j]; as f4v: index i*12 + p*4 + fg*2 (+1)
    f4v* o4 = (f4v*)out;
    long ob = (long)i * 12 + fg * 2;
    if (usel == 0) {
        f4v r0 = {acc[0][0], acc[0][1], acc[0][2], acc[0][3]};
        f4v r1 = {acc[0][4], acc[0][5], acc[0][6], acc[0][7]};
        f4v r4 = {acc[2][0], acc[2][1], acc[2][2], acc[2][3]};
        f4v r5 = {acc[2][4], acc[2][5], acc[2][6], acc[2][7]};
        o4[ob + 0] = r0;
        o4[ob + 1] = r1;
        o4[ob + 8] = r4;
        o4[ob + 9] = r5;
    } else {
        f4v r2 = {acc[1][0], acc[1][1], acc[1][2], acc[1][3]};
        f4v r3 = {acc[1][4], acc[1][5], acc[1][6], acc[1][7]};
        o4[ob + 4] = r2;
        o4[ob + 5] = r3;
    }
}

// Fallback sampler (workspace too small for fp16 L0 copy): plain loads,
// f32 texture for level 0.
__global__ __launch_bounds__(256, 4) void tm_sample_fb(const float* __restrict__ x,
                                                       const float* __restrict__ level,
                                                       const float* __restrict__ tex0,
                                                       const _Float16* __restrict__ wsh,
                                                       float* __restrict__ out, int n) {
    int t = blockIdx.x * blockDim.x + threadIdx.x;
    int i = t >> 2;
    if (i >= n) return;
    int fg = t & 1;
    int usel = (t >> 1) & 1;

    float px = x[3 * i + 0];
    float py = x[3 * i + 1];
    float pz = x[3 * i + 2];
    float lev = fminf(fmaxf(level[i], 0.0f), (float)(NLEV - 1));
    float l0f = floorf(lev);
    float frac = lev - l0f;
    int l0 = (int)l0f;
    int k1 = min(l0 + 1, NLEV - 1);

    float uu[3] = {py, px, px};
    float vv[3] = {pz, pz, py};
    int rr[2] = {BASE >> l0, BASE >> k1};
    const _Float16* texs[2];
    texs[0] = (l0 == 0) ? wsh : (wsh + moff(l0));   // l0==0 handled by f32 path
    texs[1] = wsh + moff(k1);

    h8 tvh[2][3][2];
    float wu[2][3], fvv[2][3];

#pragma unroll
    for (int s = 0; s < 2; ++s) {
        int r = rr[s];
        float rf = (float)r;
        const h8* t8 = (const h8*)texs[s];
        bool f32path = (s == 0) && (l0 == 0);
#pragma unroll
        for (int p = 0; p < 3; ++p) {
            float cu = uu[p] * rf - 0.5f;
            float cv = vv[p] * rf - 0.5f;
            float fu0 = floorf(cu), fv0 = floorf(cv);
            float fu = cu - fu0, fv = cv - fv0;
            int iu0 = (int)fu0, iv0 = (int)fv0;
            int u0 = min(max(iu0, 0), r - 1);
            int u1 = min(max(iu0 + 1, 0), r - 1);
            int v0 = min(max(iv0, 0), r - 1);
            int v1 = min(max(iv0 + 1, 0), r - 1);
            int u_ = usel ? u1 : u0;
            wu[s][p] = usel ? fu : (1.0f - fu);
            fvv[s][p] = fv;
            long pb = (long)p * r * r;
            long ti0 = pb + (long)v0 * r + u_;
            long ti1 = pb + (long)v1 * r + u_;
            if (f32path) {
                const f4v* t4 = (const f4v*)tex0;
                f4v a = t4[ti0 * 4 + fg * 2], b = t4[ti0 * 4 + fg * 2 + 1];
                f4v c = t4[ti1 * 4 + fg * 2], d = t4[ti1 * 4 + fg * 2 + 1];
                h8 A, B;
#pragma unroll
                for (int j = 0; j < 4; ++j) {
                    A[j] = (_Float16)a[j]; A[4 + j] = (_Float16)b[j];
                    B[j] = (_Float16)c[j]; B[4 + j] = (_Float16)d[j];
                }
                tvh[s][p][0] = A;
                tvh[s][p][1] = B;
            } else {
                tvh[s][p][0] = t8[ti0 * 2 + fg];
                tvh[s][p][1] = t8[ti1 * 2 + fg];
            }
        }
    }

    float lw[2] = {1.0f - frac, frac};
    float acc[3][8];
#pragma unroll
    for (int p = 0; p < 3; ++p)
#pragma unroll
        for (int j = 0; j < 8; ++j) acc[p][j] = 0.f;

#pragma unroll
    for (int s = 0; s < 2; ++s)
#pragma unroll
        for (int p = 0; p < 3; ++p) {
            float w0 = (1.0f - fvv[s][p]) * wu[s][p] * lw[s];
            float w1 = fvv[s][p] * wu[s][p] * lw[s];
#pragma unroll
            for (int j = 0; j < 8; ++j)
                acc[p][j] += (float)tvh[s][p][0][j] * w0 + (float)tvh[s][p][1][j] * w1;
        }

#pragma unroll
    for (int p = 0; p < 3; ++p)
#pragma unroll
        for (int j = 0; j < 8; ++j)
            acc[p][j] += __shfl_xor(acc[p][j], 2, 64);

    f4v* o4 = (f4v*)out;
    long ob = (long)i * 12 + fg * 2;
    if (usel == 0) {
        f4v r0 = {acc[0][0], acc[0][1], acc[0][2], acc[0][3]};
        f4v r1 = {acc[0][4], acc[0][5], acc[0][6], acc[0][7]};
        f4v r4 = {acc[2][0], acc[2][1], acc[2][2], acc[2][3]};
        f4v r5 = {acc[2][4], acc[2][5], acc[2][6], acc[2][7]};
        o4[ob + 0] = r0;
        o4[ob + 1] = r1;
        o4[ob + 8] = r4;
        o4[ob + 9] = r5;
    } else {
        f4v r2 = {acc[1][0], acc[1][1], acc[1][2], acc[1][3]};
        f4v r3 = {acc[1][4], acc[1][5], acc[1][6], acc[1][7]};
        o4[ob + 4] = r2;
        o4[ob + 5] = r3;
    }
}

extern "C" void kernel_launch(void* const* d_in, const int* in_sizes, int n_in,
                              void* d_out, int out_size, void* d_ws, size_t ws_size,
                              hipStream_t stream) {
    const float* x     = (const float*)d_in[0];
    const float* level = (const float*)d_in[1];
    const float* tex   = (const float*)d_in[2];
    float* out = (float*)d_out;
    _Float16* wsh = (_Float16*)d_ws;
    int n = in_sizes[0] / 3;

    bool full = ws_size >= (size_t)WS_NEED_FULL;

    if (full) {
        // fused fp16 L0 copy + mip1 (single pass over the f32 texture)
        int total = 3 * (BASE / 2) * (BASE / 2) * 2;
        cvt_ds1<<<(total + 255) / 256, 256, 0, stream>>>(tex, wsh + L0_OFF, wsh + moff(1));
    } else {
        int r2 = BASE >> 1;
        int total = 3 * r2 * r2 * 2;
        ds16_first<<<(total + 255) / 256, 256, 0, stream>>>(tex, wsh + moff(1), r2);
    }
    for (int k = 2; k < NLEV; ++k) {
        int r2 = BASE >> k;
        int total = 3 * r2 * r2 * 2;
        ds16<<<(total + 255) / 256, 256, 0, stream>>>(wsh + moff(k - 1), wsh + moff(k), r2);
    }

    long tt = (long)n * 4;
    int blocks = (int)((tt + 255) / 256);
    if (full)
        tm_sample_asm<<<blocks, 256, 0, stream>>>(x, level, wsh, out, n);
    else
        tm_sample_fb<<<blocks, 256, 0, stream>>>(x, level, tex, wsh, out, n);
}

// Round 8
// 141.885 us; speedup vs baseline: 1.1170x; 1.0714x over previous
//
#include <hip/hip_runtime.h>
#include <hip/hip_fp16.h>

#define NLEV 8
#define BASE 512

typedef _Float16 h8 __attribute__((ext_vector_type(8)));
typedef float f4v __attribute__((ext_vector_type(4)));
typedef signed char c8 __attribute__((ext_vector_type(8)));

#define QSCALE 12700.0f

// byte offset of int8 mip level k inside qpyr
__host__ __device__ __forceinline__ long qoff(int k) {
    return (k == 0) ? 0L : (12582912L + 4194304L - (4194304L >> (2 * k - 2)));
}
#define QPYR_BYTES 16776960L
// fp16 mip staging (halves), k>=1; lives after the int8 pyramid
__host__ __device__ __forceinline__ long moff(int k) {
    return 4194304L - (4194304L >> (2 * k - 2));
}
#define MIPS_HALVES 4194048L
#define WS_NEED (QPYR_BYTES + MIPS_HALVES * 2)

// -------- mip build (fp16 chain, exact f32 means rounded once per level) ----
__global__ __launch_bounds__(256) void ds16_first(const float* __restrict__ src,
                                                  _Float16* __restrict__ dst, int r2) {
    int idx = blockIdx.x * blockDim.x + threadIdx.x;
    int total = 3 * r2 * r2 * 2;
    if (idx >= total) return;
    int g = idx & 1;
    int rest = idx >> 1;
    int u = rest % r2; rest /= r2;
    int v = rest % r2;
    int p = rest / r2;
    int rs = r2 * 2;
    const f4v* s4 = (const f4v*)src;
    long t00 = ((long)p * rs + 2 * v) * rs + 2 * u;
    long t01 = t00 + 1, t10 = t00 + rs, t11 = t10 + 1;
    f4v a0 = s4[t00 * 4 + g * 2], a1 = s4[t00 * 4 + g * 2 + 1];
    f4v b0 = s4[t01 * 4 + g * 2], b1 = s4[t01 * 4 + g * 2 + 1];
    f4v c0 = s4[t10 * 4 + g * 2], c1 = s4[t10 * 4 + g * 2 + 1];
    f4v d0 = s4[t11 * 4 + g * 2], d1 = s4[t11 * 4 + g * 2 + 1];
    h8 o;
#pragma unroll
    for (int j = 0; j < 4; ++j) {
        o[j]     = (_Float16)((a0[j] + b0[j] + c0[j] + d0[j]) * 0.25f);
        o[4 + j] = (_Float16)((a1[j] + b1[j] + c1[j] + d1[j]) * 0.25f);
    }
    ((h8*)dst)[idx] = o;
}

__global__ __launch_bounds__(256) void ds16(const _Float16* __restrict__ src,
                                            _Float16* __restrict__ dst, int r2) {
    int idx = blockIdx.x * blockDim.x + threadIdx.x;
    int total = 3 * r2 * r2 * 2;
    if (idx >= total) return;
    int g = idx & 1;
    int rest = idx >> 1;
    int u = rest % r2; rest /= r2;
    int v = rest % r2;
    int p = rest / r2;
    int rs = r2 * 2;
    const h8* s8 = (const h8*)src;
    long t00 = ((long)p * rs + 2 * v) * rs + 2 * u;
    long t01 = t00 + 1, t10 = t00 + rs, t11 = t10 + 1;
    h8 A = s8[t00 * 2 + g], B = s8[t01 * 2 + g], C = s8[t10 * 2 + g], D = s8[t11 * 2 + g];
    h8 o;
#pragma unroll
    for (int j = 0; j < 8; ++j)
        o[j] = (_Float16)(((float)A[j] + (float)B[j] + (float)C[j] + (float)D[j]) * 0.25f);
    ((h8*)dst)[idx] = o;
}

// -------- quantize: f32 L0 -> int8; fp16 mips -> int8 ----------------------
__global__ __launch_bounds__(256) void quant_l0(const float* __restrict__ src,
                                                signed char* __restrict__ q) {
    long idx = (long)blockIdx.x * blockDim.x + threadIdx.x;
    if (idx >= 12582912L / 8) return;
    const f4v* s = (const f4v*)src;
    f4v a = s[idx * 2], b = s[idx * 2 + 1];
    c8 o;
#pragma unroll
    for (int j = 0; j < 4; ++j) {
        o[j]     = (signed char)(int)rintf(a[j] * QSCALE);
        o[4 + j] = (signed char)(int)rintf(b[j] * QSCALE);
    }
    ((c8*)q)[idx] = o;
}

__global__ __launch_bounds__(256) void quant_mips(const _Float16* __restrict__ h,
                                                  signed char* __restrict__ q) {
    long idx = (long)blockIdx.x * blockDim.x + threadIdx.x;
    if (idx >= MIPS_HALVES / 8) return;
    h8 v = ((const h8*)h)[idx];
    c8 o;
#pragma unroll
    for (int j = 0; j < 8; ++j)
        o[j] = (signed char)(int)rintf((float)v[j] * QSCALE);
    ((c8*)(q + 12582912L))[idx] = o;
}

// -------- sampler: int8 pyramid, 4 lanes per point --------------------------
// lane = i*4 + usel*2 + fg.  fg owns 8 features (8 B int8); usel owns u-column.
__global__ __launch_bounds__(256) void tm_sample_q(const float* __restrict__ x,
                                                   const float* __restrict__ level,
                                                   const signed char* __restrict__ qpyr,
                                                   float* __restrict__ out, int n) {
    int t = blockIdx.x * blockDim.x + threadIdx.x;
    int i = t >> 2;
    if (i >= n) return;
    int fg = t & 1;
    int usel = (t >> 1) & 1;

    float px = x[3 * i + 0];
    float py = x[3 * i + 1];
    float pz = x[3 * i + 2];
    float lev = fminf(fmaxf(level[i], 0.0f), (float)(NLEV - 1));
    float l0f = floorf(lev);
    float frac = lev - l0f;
    int l0 = (int)l0f;
    int k1 = min(l0 + 1, NLEV - 1);

    float uu[3] = {py, px, px};
    float vv[3] = {pz, pz, py};
    int rr[2] = {BASE >> l0, BASE >> k1};
    const signed char* qb[2] = {qpyr + qoff(l0), qpyr + qoff(k1)};
    // fold level weight and dequant scale into the per-load weights
    const float QINV = 1.0f / QSCALE;
    float lw[2] = {(1.0f - frac) * QINV, frac * QINV};

    c8 tq[12];
    float wgt[12];

#pragma unroll
    for (int s = 0; s < 2; ++s) {
        int r = rr[s];
        float rf = (float)r;
#pragma unroll
        for (int p = 0; p < 3; ++p) {
            float cu = uu[p] * rf - 0.5f;
            float cv = vv[p] * rf - 0.5f;
            float fu0 = floorf(cu), fv0 = floorf(cv);
            float fu = cu - fu0, fv = cv - fv0;
            int iu0 = (int)fu0, iv0 = (int)fv0;
            int u0 = min(max(iu0, 0), r - 1);
            int u1 = min(max(iu0 + 1, 0), r - 1);
            int v0 = min(max(iv0, 0), r - 1);
            int v1 = min(max(iv0 + 1, 0), r - 1);
            int u_ = usel ? u1 : u0;
            float wu_ = usel ? fu : (1.0f - fu);
            long pb = (long)p * r * r;
            long b0 = (pb + (long)v0 * r + u_) * 16 + fg * 8;
            long b1 = (pb + (long)v1 * r + u_) * 16 + fg * 8;
            int id = s * 6 + p * 2;
            tq[id + 0] = *(const c8*)(qb[s] + b0);
            tq[id + 1] = *(const c8*)(qb[s] + b1);
            wgt[id + 0] = (1.0f - fv) * wu_ * lw[s];
            wgt[id + 1] = fv * wu_ * lw[s];
        }
    }

    float acc[3][8];
#pragma unroll
    for (int p = 0; p < 3; ++p)
#pragma unroll
        for (int j = 0; j < 8; ++j) acc[p][j] = 0.f;

#pragma unroll
    for (int s = 0; s < 2; ++s)
#pragma unroll
        for (int p = 0; p < 3; ++p) {
            int id = s * 6 + p * 2;
            float w0 = wgt[id + 0], w1 = wgt[id + 1];
#pragma unroll
            for (int j = 0; j < 8; ++j)
                acc[p][j] += (float)tq[id + 0][j] * w0 + (float)tq[id + 1][j] * w1;
        }

    // merge u0/u1 partials across the usel pair (lane ^ 2)
#pragma unroll
    for (int p = 0; p < 3; ++p)
#pragma unroll
        for (int j = 0; j < 8; ++j)
            acc[p][j] += __shfl_xor(acc[p][j], 2, 64);

    // out[i*48 + p*16 + fg*8 + j]; as f4v: index i*12 + p*4 + fg*2 (+0/1)
    f4v* o4 = (f4v*)out;
    long ob = (long)i * 12 + fg * 2;
    if (usel == 0) {
        f4v r0 = {acc[0][0], acc[0][1], acc[0][2], acc[0][3]};
        f4v r1 = {acc[0][4], acc[0][5], acc[0][6], acc[0][7]};
        f4v r4 = {acc[2][0], acc[2][1], acc[2][2], acc[2][3]};
        f4v r5 = {acc[2][4], acc[2][5], acc[2][6], acc[2][7]};
        o4[ob + 0] = r0;
        o4[ob + 1] = r1;
        o4[ob + 8] = r4;
        o4[ob + 9] = r5;
    } else {
        f4v r2 = {acc[1][0], acc[1][1], acc[1][2], acc[1][3]};
        f4v r3 = {acc[1][4], acc[1][5], acc[1][6], acc[1][7]};
        o4[ob + 4] = r2;
        o4[ob + 5] = r3;
    }
}

extern "C" void kernel_launch(void* const* d_in, const int* in_sizes, int n_in,
                              void* d_out, int out_size, void* d_ws, size_t ws_size,
                              hipStream_t stream) {
    const float* x     = (const float*)d_in[0];
    const float* level = (const float*)d_in[1];
    const float* tex   = (const float*)d_in[2];
    float* out = (float*)d_out;
    signed char* qpyr = (signed char*)d_ws;
    _Float16* wsh = (_Float16*)((char*)d_ws + QPYR_BYTES);
    int n = in_sizes[0] / 3;

    // fp16 mip chain (staging)
    {
        int r2 = BASE >> 1;
        int total = 3 * r2 * r2 * 2;
        ds16_first<<<(total + 255) / 256, 256, 0, stream>>>(tex, wsh + moff(1), r2);
    }
    for (int k = 2; k < NLEV; ++k) {
        int r2 = BASE >> k;
        int total = 3 * r2 * r2 * 2;
        ds16<<<(total + 255) / 256, 256, 0, stream>>>(wsh + moff(k - 1), wsh + moff(k), r2);
    }
    // quantize: L0 from f32 texture, mips from fp16 chain
    {
        long tot = 12582912L / 8;
        quant_l0<<<(int)((tot + 255) / 256), 256, 0, stream>>>(tex, qpyr);
        long tot2 = MIPS_HALVES / 8;
        quant_mips<<<(int)((tot2 + 255) / 256), 256, 0, stream>>>(wsh, qpyr);
    }

    long tt = (long)n * 4;
    int blocks = (int)((tt + 255) / 256);
    tm_sample_q<<<blocks, 256, 0, stream>>>(x, level, qpyr, out, n);
}

// Round 9
// 141.282 us; speedup vs baseline: 1.1218x; 1.0043x over previous
//
#include <hip/hip_runtime.h>
#include <hip/hip_fp16.h>

#define NLEV 8
#define BASE 512

typedef _Float16 h8 __attribute__((ext_vector_type(8)));
typedef float f4v __attribute__((ext_vector_type(4)));
typedef signed char c8 __attribute__((ext_vector_type(8)));

#define QSCALE 12700.0f

// byte offset of int8 mip level k inside qpyr (L0 at 0, mips packed after)
__host__ __device__ __forceinline__ long qoff(int k) {
    return (k == 0) ? 0L : (12582912L + 4194304L - (4194304L >> (2 * k - 2)));
}
#define QPYR_BYTES 16776960L
#define QOFF4      16711680L     // qoff(4); levels 4..7 are the last 65280 B
#define LDSB       65280
// fp16 mip staging (halves), k>=1; lives after the int8 pyramid
__host__ __device__ __forceinline__ long moff(int k) {
    return 4194304L - (4194304L >> (2 * k - 2));
}
#define MIPS_HALVES 4194048L

// -------- fused mip build + quantize ---------------------------------------
// mip1 from f32 L0; also quantizes the 4 L0 texel-halves it reads and the
// mip1 result to int8 (removes the separate quant passes over 48 MB).
__global__ __launch_bounds__(256) void ds16_first(const float* __restrict__ src,
                                                  _Float16* __restrict__ dst,
                                                  signed char* __restrict__ qpyr, int r2) {
    int idx = blockIdx.x * blockDim.x + threadIdx.x;
    int total = 3 * r2 * r2 * 2;
    if (idx >= total) return;
    int g = idx & 1;
    int rest = idx >> 1;
    int u = rest % r2; rest /= r2;
    int v = rest % r2;
    int p = rest / r2;
    int rs = r2 * 2;
    const f4v* s4 = (const f4v*)src;
    long t00 = ((long)p * rs + 2 * v) * rs + 2 * u;
    long t01 = t00 + 1, t10 = t00 + rs, t11 = t10 + 1;
    f4v a0 = s4[t00 * 4 + g * 2], a1 = s4[t00 * 4 + g * 2 + 1];
    f4v b0 = s4[t01 * 4 + g * 2], b1 = s4[t01 * 4 + g * 2 + 1];
    f4v c0 = s4[t10 * 4 + g * 2], c1 = s4[t10 * 4 + g * 2 + 1];
    f4v d0 = s4[t11 * 4 + g * 2], d1 = s4[t11 * 4 + g * 2 + 1];
    h8 o;
    c8 qa, qb_, qc, qd, qo;
#pragma unroll
    for (int j = 0; j < 4; ++j) {
        float m0 = (a0[j] + b0[j] + c0[j] + d0[j]) * 0.25f;
        float m1 = (a1[j] + b1[j] + c1[j] + d1[j]) * 0.25f;
        o[j] = (_Float16)m0; o[4 + j] = (_Float16)m1;
        qo[j] = (signed char)(int)rintf(m0 * QSCALE);
        qo[4 + j] = (signed char)(int)rintf(m1 * QSCALE);
        qa[j] = (signed char)(int)rintf(a0[j] * QSCALE); qa[4 + j] = (signed char)(int)rintf(a1[j] * QSCALE);
        qb_[j] = (signed char)(int)rintf(b0[j] * QSCALE); qb_[4 + j] = (signed char)(int)rintf(b1[j] * QSCALE);
        qc[j] = (signed char)(int)rintf(c0[j] * QSCALE); qc[4 + j] = (signed char)(int)rintf(c1[j] * QSCALE);
        qd[j] = (signed char)(int)rintf(d0[j] * QSCALE); qd[4 + j] = (signed char)(int)rintf(d1[j] * QSCALE);
    }
    ((h8*)dst)[idx] = o;
    // int8 L0 writes (8 B each at texel*16 + g*8)
    *(c8*)(qpyr + t00 * 16 + g * 8) = qa;
    *(c8*)(qpyr + t01 * 16 + g * 8) = qb_;
    *(c8*)(qpyr + t10 * 16 + g * 8) = qc;
    *(c8*)(qpyr + t11 * 16 + g * 8) = qd;
    // int8 mip1
    *(c8*)(qpyr + qoff(1) + (long)idx * 8) = qo;
}

// fp16 mip -> fp16 mip (+ int8 quantized copy of the new level)
__global__ __launch_bounds__(256) void ds16(const _Float16* __restrict__ src,
                                            _Float16* __restrict__ dst,
                                            signed char* __restrict__ qlvl, int r2) {
    int idx = blockIdx.x * blockDim.x + threadIdx.x;
    int total = 3 * r2 * r2 * 2;
    if (idx >= total) return;
    int g = idx & 1;
    int rest = idx >> 1;
    int u = rest % r2; rest /= r2;
    int v = rest % r2;
    int p = rest / r2;
    int rs = r2 * 2;
    const h8* s8 = (const h8*)src;
    long t00 = ((long)p * rs + 2 * v) * rs + 2 * u;
    long t01 = t00 + 1, t10 = t00 + rs, t11 = t10 + 1;
    h8 A = s8[t00 * 2 + g], B = s8[t01 * 2 + g], C = s8[t10 * 2 + g], D = s8[t11 * 2 + g];
    h8 o;
    c8 q;
#pragma unroll
    for (int j = 0; j < 8; ++j) {
        float m = ((float)A[j] + (float)B[j] + (float)C[j] + (float)D[j]) * 0.25f;
        o[j] = (_Float16)m;
        q[j] = (signed char)(int)rintf(m * QSCALE);
    }
    ((h8*)dst)[idx] = o;
    *(c8*)(qlvl + (long)idx * 8) = q;
}

// -------- sampler: persistent blocks, levels 4-7 resident in LDS -----------
// 1024 threads/block, 2 blocks/CU (LDS 65280 B). 4 lanes per point:
// lane = i*4 + usel*2 + fg. fg owns 8 features; usel owns the u-column.
__global__ __launch_bounds__(1024, 2) void tm_sample_l(const float* __restrict__ x,
                                                       const float* __restrict__ level,
                                                       const signed char* __restrict__ qpyr,
                                                       float* __restrict__ out, int n) {
    __shared__ alignas(16) signed char lm[LDSB];
    {
        const f4v* src = (const f4v*)(qpyr + QOFF4);
        f4v* dst = (f4v*)lm;
        for (int idx = threadIdx.x; idx < LDSB / 16; idx += 1024)
            dst[idx] = src[idx];
    }
    __syncthreads();

    int fg = threadIdx.x & 1;
    int usel = (threadIdx.x >> 1) & 1;
    int pid = threadIdx.x >> 2;          // 0..255 point slot within block

    for (long base = (long)blockIdx.x * 256; base < (long)n; base += (long)gridDim.x * 256) {
        int i = (int)(base + pid);
        if (i < n) {
            float px = x[3 * i + 0];
            float py = x[3 * i + 1];
            float pz = x[3 * i + 2];
            float lev = fminf(fmaxf(level[i], 0.0f), (float)(NLEV - 1));
            float l0f = floorf(lev);
            float frac = lev - l0f;
            int l0 = (int)l0f;
            int k1 = min(l0 + 1, NLEV - 1);
            int kk[2] = {l0, k1};

            float uu[3] = {py, px, px};
            float vv[3] = {pz, pz, py};
            const float QINV = 1.0f / QSCALE;
            float lw[2] = {(1.0f - frac) * QINV, frac * QINV};

            c8 tq[12];
            float wgt[12];

#pragma unroll
            for (int s = 0; s < 2; ++s) {
                int k = kk[s];
                int r = BASE >> k;
                float rf = (float)r;
                bool in_lds = (k >= 4);
                long gbase = qoff(k);
                int lbase = (int)(gbase - QOFF4);
#pragma unroll
                for (int p = 0; p < 3; ++p) {
                    float cu = uu[p] * rf - 0.5f;
                    float cv = vv[p] * rf - 0.5f;
                    float fu0 = floorf(cu), fv0 = floorf(cv);
                    float fu = cu - fu0, fv = cv - fv0;
                    int iu0 = (int)fu0, iv0 = (int)fv0;
                    int u0 = min(max(iu0, 0), r - 1);
                    int u1 = min(max(iu0 + 1, 0), r - 1);
                    int v0 = min(max(iv0, 0), r - 1);
                    int v1 = min(max(iv0 + 1, 0), r - 1);
                    int u_ = usel ? u1 : u0;
                    float wu_ = usel ? fu : (1.0f - fu);
                    int pb = p * r * r;
                    int b0 = (pb + v0 * r + u_) * 16 + fg * 8;
                    int b1 = (pb + v1 * r + u_) * 16 + fg * 8;
                    int id = s * 6 + p * 2;
                    if (in_lds) {
                        tq[id + 0] = *(const c8*)(lm + lbase + b0);
                        tq[id + 1] = *(const c8*)(lm + lbase + b1);
                    } else {
                        tq[id + 0] = *(const c8*)(qpyr + gbase + b0);
                        tq[id + 1] = *(const c8*)(qpyr + gbase + b1);
                    }
                    wgt[id + 0] = (1.0f - fv) * wu_ * lw[s];
                    wgt[id + 1] = fv * wu_ * lw[s];
                }
            }

            float acc[3][8];
#pragma unroll
            for (int p = 0; p < 3; ++p)
#pragma unroll
                for (int j = 0; j < 8; ++j) acc[p][j] = 0.f;

#pragma unroll
            for (int s = 0; s < 2; ++s)
#pragma unroll
                for (int p = 0; p < 3; ++p) {
                    int id = s * 6 + p * 2;
                    float w0 = wgt[id + 0], w1 = wgt[id + 1];
#pragma unroll
                    for (int j = 0; j < 8; ++j)
                        acc[p][j] += (float)tq[id + 0][j] * w0 + (float)tq[id + 1][j] * w1;
                }

            // merge u0/u1 partials across the usel pair (lane ^ 2)
#pragma unroll
            for (int p = 0; p < 3; ++p)
#pragma unroll
                for (int j = 0; j < 8; ++j)
                    acc[p][j] += __shfl_xor(acc[p][j], 2, 64);

            // out[i*48 + p*16 + fg*8 + j]; as f4v: i*12 + p*4 + fg*2 (+0/1)
            f4v* o4 = (f4v*)out;
            long ob = (long)i * 12 + fg * 2;
            if (usel == 0) {
                f4v r0 = {acc[0][0], acc[0][1], acc[0][2], acc[0][3]};
                f4v r1 = {acc[0][4], acc[0][5], acc[0][6], acc[0][7]};
                f4v r4 = {acc[2][0], acc[2][1], acc[2][2], acc[2][3]};
                f4v r5 = {acc[2][4], acc[2][5], acc[2][6], acc[2][7]};
                o4[ob + 0] = r0;
                o4[ob + 1] = r1;
                o4[ob + 8] = r4;
                o4[ob + 9] = r5;
            } else {
                f4v r2 = {acc[1][0], acc[1][1], acc[1][2], acc[1][3]};
                f4v r3 = {acc[1][4], acc[1][5], acc[1][6], acc[1][7]};
                o4[ob + 4] = r2;
                o4[ob + 5] = r3;
            }
        }
    }
}

extern "C" void kernel_launch(void* const* d_in, const int* in_sizes, int n_in,
                              void* d_out, int out_size, void* d_ws, size_t ws_size,
                              hipStream_t stream) {
    const float* x     = (const float*)d_in[0];
    const float* level = (const float*)d_in[1];
    const float* tex   = (const float*)d_in[2];
    float* out = (float*)d_out;
    signed char* qpyr = (signed char*)d_ws;
    _Float16* wsh = (_Float16*)((char*)d_ws + QPYR_BYTES);
    int n = in_sizes[0] / 3;

    // fused mip build + int8 quantization
    {
        int r2 = BASE >> 1;
        int total = 3 * r2 * r2 * 2;
        ds16_first<<<(total + 255) / 256, 256, 0, stream>>>(tex, wsh + moff(1), qpyr, r2);
    }
    for (int k = 2; k < NLEV; ++k) {
        int r2 = BASE >> k;
        int total = 3 * r2 * r2 * 2;
        ds16<<<(total + 255) / 256, 256, 0, stream>>>(wsh + moff(k - 1), wsh + moff(k),
                                                      qpyr + qoff(k), r2);
    }

    // persistent sampler: 512 blocks x 1024 threads (2 blocks/CU, LDS-resident mips 4-7)
    tm_sample_l<<<512, 1024, 0, stream>>>(x, level, qpyr, out, n);
}